// Round 13
// baseline (320.221 us; speedup 1.0000x reference)
//
#include <hip/hip_runtime.h>

#define TT 100
#define BB 2048
#define NI 3
#define NU 128
#define NB 256
#define NPC 256
#define NHD 12

typedef __attribute__((ext_vector_type(8))) short short8;
typedef __attribute__((ext_vector_type(4))) float f32x4;

__device__ __forceinline__ float fast_sigmoid(float x) {
  return 1.0f / (1.0f + __expf(-x));
}
__device__ __forceinline__ float fast_tanh(float x) {
  return 1.0f - 2.0f / (__expf(2.0f * x) + 1.0f);
}
__device__ __forceinline__ short f2bf(float f) {
  uint32_t u = __float_as_uint(f);
  u += 0x7FFF + ((u >> 16) & 1);  // RNE
  return (short)(u >> 16);
}
__device__ __forceinline__ float bf2f(short s) {
  return __uint_as_float(((uint32_t)(uint16_t)s) << 16);
}
// HW packed f32->bf16 (RNE), 1 instruction for 2 values.
__device__ __forceinline__ uint32_t cvt_pk_bf16(float lo, float hi) {
  uint32_t r;
  asm("v_cvt_pk_bf16_f32 %0, %1, %2" : "=v"(r) : "v"(lo), "v"(hi));
  return r;
}
// LDS-only barrier: leaves global (vmcnt) stores in flight across the barrier.
__device__ __forceinline__ void lds_barrier() {
  asm volatile("s_waitcnt lgkmcnt(0)" ::: "memory");
  __builtin_amdgcn_s_barrier();
}

// ---------------------------------------------------------------------------
// h0 = concat(init_pc, init_hd) @ W_embed + b_embed     [B, NU]
// ---------------------------------------------------------------------------
__global__ __launch_bounds__(256) void embed_kernel(
    const float* __restrict__ init_pc, const float* __restrict__ init_hd,
    const float* __restrict__ W_embed, const float* __restrict__ b_embed,
    float* __restrict__ h0) {
  __shared__ float pcs[2][NPC];
  __shared__ float hds[2][NHD];
  const int tid = threadIdx.x;
  const int b0 = blockIdx.x * 2;

  for (int idx = tid; idx < 2 * NPC; idx += 256)
    pcs[idx >> 8][idx & 255] =
        init_pc[(size_t)(b0 + (idx >> 8)) * NPC + (idx & 255)];
  if (tid < 2 * NHD) {
    int rr = tid / NHD, cc = tid - rr * NHD;
    hds[rr][cc] = init_hd[(size_t)(b0 + rr) * NHD + cc];
  }
  __syncthreads();

  const int half = tid >> 7;
  const int j = tid & 127;
  const float* Wp = W_embed + j;
  float a0 = 0.f, a1 = 0.f, a2 = 0.f, a3 = 0.f;
#pragma unroll 4
  for (int k = 0; k < NPC; k += 4) {
    a0 = fmaf(pcs[half][k + 0], Wp[(k + 0) * NU], a0);
    a1 = fmaf(pcs[half][k + 1], Wp[(k + 1) * NU], a1);
    a2 = fmaf(pcs[half][k + 2], Wp[(k + 2) * NU], a2);
    a3 = fmaf(pcs[half][k + 3], Wp[(k + 3) * NU], a3);
  }
#pragma unroll
  for (int k = 0; k < NHD; ++k)
    a0 = fmaf(hds[half][k], Wp[(NPC + k) * NU], a0);
  float acc = b_embed[j] + ((a0 + a1) + (a2 + a3));
  h0[(size_t)(b0 + half) * NU + j] = acc;
}

// ---------------------------------------------------------------------------
// Pre-pack GRU weights as bf16 MFMA B-fragments into workspace.
//   f in [0,96):    hi of U_g, g=f>>5 (0=Uz,1=Ur,2=Uh), nt=(f>>2)&7, kt=f&3
//   f in [96,128):  lo of Uh, nt=(f>>2)&7, kt=f&3
//   f in [128,152): augmented x-proj frag: w=f-128, g=w>>3, nt=w&7,
//                   B[k][col]: k<3 -> W_g[k][col], k==3 -> bias_g[col], else 0
// ---------------------------------------------------------------------------
__global__ __launch_bounds__(256) void prepack_gru_kernel(
    const float* __restrict__ Uz, const float* __restrict__ Ur,
    const float* __restrict__ Uh, const float* __restrict__ Wz,
    const float* __restrict__ Wr, const float* __restrict__ Wh,
    const float* __restrict__ bz, const float* __restrict__ br,
    const float* __restrict__ bh, short* __restrict__ gfrags) {
  int t = blockIdx.x * 256 + threadIdx.x;
  if (t >= 152 * 64) return;
  const int f = t >> 6, lane = t & 63;
  const int ln15 = lane & 15, g4 = lane >> 4;
  short8 p;
  if (f < 128) {
    const int g = f >> 5;  // 3 for the Uh-lo band
    const int nt = (f >> 2) & 7, kt = f & 3;
    const float* U = (g == 0) ? Uz : (g == 1) ? Ur : Uh;
#pragma unroll
    for (int e = 0; e < 8; ++e) {
      const float v = U[(kt * 32 + g4 * 8 + e) * NU + nt * 16 + ln15];
      const short hi = f2bf(v);
      p[e] = (f < 96) ? hi : f2bf(v - bf2f(hi));
    }
  } else {
    const int w = f - 128;
    const int g = w >> 3, nt = w & 7;
    const float* W = (g == 0) ? Wz : (g == 1) ? Wr : Wh;
    const float* bb = (g == 0) ? bz : (g == 1) ? br : bh;
    const int col = nt * 16 + ln15;
#pragma unroll
    for (int e = 0; e < 8; ++e) {
      const int k = g4 * 8 + e;
      float v = 0.0f;
      if (k < 3) v = W[k * NU + col];
      if (k == 3) v = bb[col];
      p[e] = f2bf(v);
    }
  }
  *((short8*)gfrags + (f * 64 + lane)) = p;
}

// ---------------------------------------------------------------------------
// GRU scan: R4's row-efficient skeleton + R10's lean payload (= R11 best).
// 256 blocks x 8 REAL rows (M padded 16); 512 thr = 8 waves; wave w owns
// cols [16w,16w+16) -> U slice = 16 frags (64 VGPR).
// Per wave per step: 8 ds_read_b128 (hi-only h/p planes), 19 MFMA
// (gates 1-term, h-tilde 2-term with B-side Uh-lo), x-proj folded into
// MFMA via augmented-K waug frags, cvt_pk packing, fire-and-forget stores.
// Pad rows 8-15 of the planes are never written: garbage A-rows only
// produce garbage D-rows 8-15, which are discarded (row-local MFMA).
// ---------------------------------------------------------------------------
__global__ __launch_bounds__(512, 2) void gru_fast_kernel(
    const float* __restrict__ x, const float* __restrict__ h0,
    const short* __restrict__ gfrags, float* __restrict__ states,
    float* __restrict__ final_state) {
  __shared__ short h_hi[16 * 128];  // 4 KB (rows 8-15 uninitialized pad)
  __shared__ short p_hi[16 * 128];  // 4 KB
  __shared__ short8 waug[24 * 64];  // 24 KB
  __shared__ float xs[TT][8][4];    // 12.8 KB, [r][3] = 1.0 (bias row)

  const int tid = threadIdx.x;
  const int lane = tid & 63;
  const int w = tid >> 6;  // 0..7 == nt
  const int ln15 = lane & 15, g4 = lane >> 4;
  const int col = w * 16 + ln15;
  const int row0 = blockIdx.x * 8;

  // ---- stage Waug fragments + x for all T ----
  for (int i = tid; i < 24 * 64; i += 512)
    waug[i] = *((const short8*)gfrags + (size_t)(128 + (i >> 6)) * 64 + (i & 63));
  for (int i = tid; i < TT * 32; i += 512) {
    const int t = i >> 5, r = (i >> 2) & 7, c = i & 3;
    ((float*)xs)[i] = (c < 3) ? x[(size_t)(t * BB + row0 + r) * NI + c] : 1.0f;
  }

  // ---- U fragments -> registers (16 frags = 64 VGPR) ----
  short8 Uzh[4], Urh[4], Uhh[4], Uhl[4];
#pragma unroll
  for (int kt = 0; kt < 4; ++kt) {
    Uzh[kt] = *((const short8*)gfrags + (size_t)(w * 4 + kt) * 64 + lane);
    Urh[kt] = *((const short8*)gfrags + (size_t)(32 + w * 4 + kt) * 64 + lane);
    Uhh[kt] = *((const short8*)gfrags + (size_t)(64 + w * 4 + kt) * 64 + lane);
    Uhl[kt] = *((const short8*)gfrags + (size_t)(96 + w * 4 + kt) * 64 + lane);
  }

  // ---- fragment byte offsets (verified swizzle) ----
  int foff[4];
#pragma unroll
  for (int kt = 0; kt < 4; ++kt)
    foff[kt] = ln15 * 256 + ((kt * 64 + g4 * 16) ^ ((ln15 & 7) << 4));
  int woff[4];  // valid for g4 < 2: rows 0-7
#pragma unroll
  for (int q = 0; q < 4; ++q) {
    const int row = g4 * 4 + q;
    woff[q] = (row & 7) * 256 + ((col * 2) ^ ((row & 7) << 4));
  }

  // ---- init h (rows 0-7 real; pad rows untouched) ----
  float hreg[4] = {0.f, 0.f, 0.f, 0.f};
  if (g4 < 2) {
#pragma unroll
    for (int q = 0; q < 4; ++q)
      hreg[q] = h0[(size_t)(row0 + g4 * 4 + q) * NU + col];
    const uint32_t pk01 = cvt_pk_bf16(hreg[0], hreg[1]);
    const uint32_t pk23 = cvt_pk_bf16(hreg[2], hreg[3]);
    *(short*)((char*)h_hi + woff[0]) = (short)pk01;
    *(short*)((char*)h_hi + woff[1]) = (short)(pk01 >> 16);
    *(short*)((char*)h_hi + woff[2]) = (short)pk23;
    *(short*)((char*)h_hi + woff[3]) = (short)(pk23 >> 16);
  }
  __syncthreads();

  const f32x4 zero = {0.f, 0.f, 0.f, 0.f};

  for (int t = 0; t < TT; ++t) {
    // ---- h A-fragments + augmented x fragment ----
    short8 ahi[4];
#pragma unroll
    for (int kt = 0; kt < 4; ++kt)
      ahi[kt] = *(const short8*)((const char*)h_hi + foff[kt]);
    short8 ax = {0, 0, 0, 0, 0, 0, 0, 0};
    {
      // A row ln15: rows 8-15 read row&7 (garbage D rows discarded anyway)
      const float4 xv = *(const float4*)&xs[t][ln15 & 7][0];
      if (g4 == 0) {
        const uint32_t a = cvt_pk_bf16(xv.x, xv.y);
        const uint32_t b = cvt_pk_bf16(xv.z, xv.w);  // xv.w = 1.0 (bias row)
        ax[0] = (short)a;
        ax[1] = (short)(a >> 16);
        ax[2] = (short)b;
        ax[3] = (short)(b >> 16);
      }
    }

    // ================= phase A: z and r gates (1-term) =================
    f32x4 zacc = __builtin_amdgcn_mfma_f32_16x16x32_bf16(
        ax, waug[(0 * 8 + w) * 64 + lane], zero, 0, 0, 0);
    f32x4 racc = __builtin_amdgcn_mfma_f32_16x16x32_bf16(
        ax, waug[(1 * 8 + w) * 64 + lane], zero, 0, 0, 0);
#pragma unroll
    for (int kt = 0; kt < 4; ++kt) {
      zacc = __builtin_amdgcn_mfma_f32_16x16x32_bf16(ahi[kt], Uzh[kt], zacc, 0, 0, 0);
      racc = __builtin_amdgcn_mfma_f32_16x16x32_bf16(ahi[kt], Urh[kt], racc, 0, 0, 0);
    }

    float zg[4];
#pragma unroll
    for (int q = 0; q < 4; ++q) zg[q] = fast_sigmoid(zacc[q]);
    if (g4 < 2) {
      float rh[4];
#pragma unroll
      for (int q = 0; q < 4; ++q) rh[q] = fast_sigmoid(racc[q]) * hreg[q];
      const uint32_t pk01 = cvt_pk_bf16(rh[0], rh[1]);
      const uint32_t pk23 = cvt_pk_bf16(rh[2], rh[3]);
      *(short*)((char*)p_hi + woff[0]) = (short)pk01;
      *(short*)((char*)p_hi + woff[1]) = (short)(pk01 >> 16);
      *(short*)((char*)p_hi + woff[2]) = (short)pk23;
      *(short*)((char*)p_hi + woff[3]) = (short)(pk23 >> 16);
    }
    lds_barrier();  // rh plane visible

    // ============ phase B: h-tilde (phi*Uhh + phi*Uhl) + update ============
    short8 phi[4];
#pragma unroll
    for (int kt = 0; kt < 4; ++kt)
      phi[kt] = *(const short8*)((const char*)p_hi + foff[kt]);
    f32x4 hacc = __builtin_amdgcn_mfma_f32_16x16x32_bf16(
        ax, waug[(2 * 8 + w) * 64 + lane], zero, 0, 0, 0);
    f32x4 hacc2 = zero;
#pragma unroll
    for (int kt = 0; kt < 4; ++kt) {
      hacc = __builtin_amdgcn_mfma_f32_16x16x32_bf16(phi[kt], Uhh[kt], hacc, 0, 0, 0);
      hacc2 = __builtin_amdgcn_mfma_f32_16x16x32_bf16(phi[kt], Uhl[kt], hacc2, 0, 0, 0);
    }
#pragma unroll
    for (int q = 0; q < 4; ++q) {
      const float htw = fast_tanh(hacc[q] + hacc2[q]);
      hreg[q] = fmaf(zg[q], htw - hreg[q], hreg[q]);
    }
    if (g4 < 2) {
      const uint32_t pk01 = cvt_pk_bf16(hreg[0], hreg[1]);
      const uint32_t pk23 = cvt_pk_bf16(hreg[2], hreg[3]);
      *(short*)((char*)h_hi + woff[0]) = (short)pk01;
      *(short*)((char*)h_hi + woff[1]) = (short)(pk01 >> 16);
      *(short*)((char*)h_hi + woff[2]) = (short)pk23;
      *(short*)((char*)h_hi + woff[3]) = (short)(pk23 >> 16);
      // fire-and-forget HBM stores (no vmcnt wait in loop)
      float* sp = states + ((size_t)t * BB + row0 + g4 * 4) * NU + col;
#pragma unroll
      for (int q = 0; q < 4; ++q) sp[q * NU] = hreg[q];
    }
    lds_barrier();  // h plane visible
  }

  if (g4 < 2) {
#pragma unroll
    for (int q = 0; q < 4; ++q)
      final_state[(size_t)(row0 + g4 * 4 + q) * NU + col] = hreg[q];
  }
}

// ---------------------------------------------------------------------------
// Pre-pack heads weights into bf16 MFMA B-fragment order (unchanged).
// ---------------------------------------------------------------------------
__global__ __launch_bounds__(256) void prepack_kernel(
    const float* __restrict__ Wb, const float* __restrict__ Wpc,
    const float* __restrict__ Whd, short* __restrict__ Wb_pack,
    short* __restrict__ Wpc_pack, short* __restrict__ Whd_pack) {
  int t = blockIdx.x * 256 + threadIdx.x;
  if (t >= 200 * 64) return;
  int fb = t >> 6, lane = t & 63;
  const float* W;
  short* out;
  int n_tile, k_tile, N, local;
  if (fb < 64) {
    W = Wb; out = Wb_pack; local = fb; n_tile = fb >> 2; k_tile = fb & 3; N = 256;
  } else if (fb < 192) {
    int f = fb - 64;
    W = Wpc; out = Wpc_pack; local = f; n_tile = f >> 3; k_tile = f & 7; N = 256;
  } else {
    int f = fb - 192;
    W = Whd; out = Whd_pack; local = f; n_tile = 0; k_tile = f; N = 12;
  }
  short8 p;
#pragma unroll
  for (int e = 0; e < 8; ++e) {
    int k = k_tile * 32 + (lane >> 4) * 8 + e;
    int colc = n_tile * 16 + (lane & 15);
    float v = (colc < N) ? W[k * N + colc] : 0.0f;
    p[e] = f2bf(v);
  }
  *((short8*)out + (local * 64 + lane)) = p;
}

// ---------------------------------------------------------------------------
// MFMA heads: 64 rows/block, 256 threads (4 waves, 16-row stripe each).
// ---------------------------------------------------------------------------
__global__ __launch_bounds__(256, 3) void heads_mfma_kernel(
    const float* __restrict__ states, const short* __restrict__ Wb_pack,
    const short* __restrict__ Wpc_pack, const short* __restrict__ Whd_pack,
    const float* __restrict__ b_pc, const float* __restrict__ b_hd,
    float* __restrict__ out_hd, float* __restrict__ out_pc,
    float* __restrict__ out_bn) {
  __shared__ short s_lds[64 * 128];   // 16 KB
  __shared__ short bn_lds[64 * 256];  // 32 KB
  const int tid = threadIdx.x;
  const size_t R0 = (size_t)blockIdx.x * 64;

  for (int c = tid; c < 1024; c += 256) {
    int row = c >> 4, s16 = c & 15;
    const float* src = states + (R0 + row) * 128 + s16 * 8;
    float4 v0 = *(const float4*)src;
    float4 v1 = *(const float4*)(src + 4);
    short8 p;
    p[0] = f2bf(v0.x); p[1] = f2bf(v0.y); p[2] = f2bf(v0.z); p[3] = f2bf(v0.w);
    p[4] = f2bf(v1.x); p[5] = f2bf(v1.y); p[6] = f2bf(v1.z); p[7] = f2bf(v1.w);
    int byte = row * 256 + ((s16 * 16) ^ ((row & 7) << 4));
    *(short8*)((char*)s_lds + byte) = p;
  }
  __syncthreads();

  const int lane = tid & 63;
  const int wave = tid >> 6;
  const int ln15 = lane & 15;
  const int ln4 = lane >> 4;
  const int r0 = wave * 16;

  {
    short8 a[4];
#pragma unroll
    for (int kt = 0; kt < 4; ++kt) {
      int byte =
          (r0 + ln15) * 256 + ((kt * 64 + ln4 * 16) ^ ((ln15 & 7) << 4));
      a[kt] = *(const short8*)((const char*)s_lds + byte);
    }
#pragma unroll
    for (int nt = 0; nt < 16; ++nt) {
      f32x4 acc = {0.f, 0.f, 0.f, 0.f};
      const short8* bp = (const short8*)Wb_pack + (nt * 4) * 64 + lane;
#pragma unroll
      for (int kt = 0; kt < 4; ++kt)
        acc = __builtin_amdgcn_mfma_f32_16x16x32_bf16(a[kt], bp[kt * 64], acc,
                                                      0, 0, 0);
      int colc = nt * 16 + ln15;
#pragma unroll
      for (int q = 0; q < 4; ++q) {
        int row = r0 + ln4 * 4 + q;
        out_bn[(R0 + row) * NB + colc] = acc[q];
        int byte = row * 512 + ((colc * 2) ^ ((row & 7) << 4));
        *(short*)((char*)bn_lds + byte) = f2bf(acc[q]);
      }
    }
  }
  __syncthreads();

  {
    short8 ab[8];
#pragma unroll
    for (int kt = 0; kt < 8; ++kt) {
      int byte =
          (r0 + ln15) * 512 + ((kt * 64 + ln4 * 16) ^ ((ln15 & 7) << 4));
      ab[kt] = *(const short8*)((const char*)bn_lds + byte);
    }
#pragma unroll
    for (int nt = 0; nt < 16; ++nt) {
      int colc = nt * 16 + ln15;
      float bias = b_pc[colc];
      f32x4 acc = {bias, bias, bias, bias};
      const short8* bp = (const short8*)Wpc_pack + (nt * 8) * 64 + lane;
#pragma unroll
      for (int kt = 0; kt < 8; ++kt)
        acc = __builtin_amdgcn_mfma_f32_16x16x32_bf16(ab[kt], bp[kt * 64], acc,
                                                      0, 0, 0);
#pragma unroll
      for (int q = 0; q < 4; ++q)
        out_pc[(R0 + r0 + ln4 * 4 + q) * NPC + colc] = acc[q];
    }
    {
      int colc = ln15;
      float bias = (colc < NHD) ? b_hd[colc] : 0.0f;
      f32x4 acc = {bias, bias, bias, bias};
      const short8* bp = (const short8*)Whd_pack + lane;
#pragma unroll
      for (int kt = 0; kt < 8; ++kt)
        acc = __builtin_amdgcn_mfma_f32_16x16x32_bf16(ab[kt], bp[kt * 64], acc,
                                                      0, 0, 0);
      if (colc < NHD) {
#pragma unroll
        for (int q = 0; q < 4; ++q)
          out_hd[(R0 + r0 + ln4 * 4 + q) * NHD + colc] = acc[q];
      }
    }
  }
}

// ---------------------------------------------------------------------------
extern "C" void kernel_launch(void* const* d_in, const int* in_sizes, int n_in,
                              void* d_out, int out_size, void* d_ws,
                              size_t ws_size, hipStream_t stream) {
  (void)in_sizes;
  (void)n_in;
  (void)out_size;
  (void)ws_size;
  const float* x = (const float*)d_in[0];
  const float* init_pc = (const float*)d_in[1];
  const float* init_hd = (const float*)d_in[2];
  const float* Wz = (const float*)d_in[3];
  const float* Wr = (const float*)d_in[4];
  const float* Wh = (const float*)d_in[5];
  const float* Uz = (const float*)d_in[6];
  const float* Ur = (const float*)d_in[7];
  const float* Uh = (const float*)d_in[8];
  const float* bz = (const float*)d_in[9];
  const float* br = (const float*)d_in[10];
  const float* bh = (const float*)d_in[11];
  const float* W_embed = (const float*)d_in[12];
  const float* b_embed = (const float*)d_in[13];
  const float* W_bneck = (const float*)d_in[14];
  const float* W_pc = (const float*)d_in[15];
  const float* b_pc = (const float*)d_in[16];
  const float* W_hd = (const float*)d_in[17];
  const float* b_hd = (const float*)d_in[18];

  float* out = (float*)d_out;
  float* out_hd = out;
  float* out_pc = out_hd + (size_t)TT * BB * NHD;
  float* out_bn = out_pc + (size_t)TT * BB * NPC;
  float* out_st = out_bn + (size_t)TT * BB * NB;
  float* out_fs = out_st + (size_t)TT * BB * NU;

  float* h0 = (float*)d_ws;                            // 1 MB
  short* Wb_pack = (short*)((char*)d_ws + (1 << 20));  // 64 KB
  short* Wpc_pack = Wb_pack + 64 * 64 * 8;             // 128 KB
  short* Whd_pack = Wpc_pack + 128 * 64 * 8;           // 8 KB
  short* gru_frags = (short*)((char*)d_ws + (1 << 20) + 200 * 1024);  // 152 KB

  prepack_kernel<<<50, 256, 0, stream>>>(W_bneck, W_pc, W_hd, Wb_pack,
                                         Wpc_pack, Whd_pack);
  prepack_gru_kernel<<<38, 256, 0, stream>>>(Uz, Ur, Uh, Wz, Wr, Wh, bz, br,
                                             bh, gru_frags);
  embed_kernel<<<BB / 2, 256, 0, stream>>>(init_pc, init_hd, W_embed, b_embed,
                                           h0);
  gru_fast_kernel<<<BB / 8, 512, 0, stream>>>(x, h0, gru_frags, out_st,
                                              out_fs);
  heads_mfma_kernel<<<(TT * BB) / 64, 256, 0, stream>>>(
      out_st, Wb_pack, Wpc_pack, Whd_pack, b_pc, b_hd, out_hd, out_pc, out_bn);
}